// Round 14
// baseline (414.082 us; speedup 1.0000x reference)
//
#include <hip/hip_runtime.h>

typedef unsigned short u16;
typedef unsigned int u32;
typedef short bf16x8 __attribute__((ext_vector_type(8)));
typedef float f32x4 __attribute__((ext_vector_type(4)));
typedef float f32x16 __attribute__((ext_vector_type(16)));

// ---------- bf16 helpers ----------
__device__ __forceinline__ float b2f(u16 v) { return __uint_as_float(((u32)v) << 16); }
__device__ __forceinline__ u16 f2b(float f) {   // round-to-nearest-even
    u32 x = __float_as_uint(f);
    return (u16)((x + 0x7fffu + ((x >> 16) & 1u)) >> 16);
}

// async global->LDS, 16B per lane: LDS dest = uniform base + lane*16
__device__ __forceinline__ void gld_lds16(const u16* g, u16* l) {
    __builtin_amdgcn_global_load_lds(
        (const __attribute__((address_space(1))) unsigned int*)g,
        (__attribute__((address_space(3))) unsigned int*)l,
        16, 0, 0);
}

#define S_LEN 256
#define B_SZ  512
#define DM    128
#define DFF   512
#define MROWS (S_LEN * B_SZ)   // 131072

// swizzled LDS address for a [row][128] bf16 tile, 16 slots of 8
__device__ __forceinline__ int sw16(int r, int d) {
    return r * 128 + ((((d >> 3) ^ (r & 15)) & 15) << 3) + (d & 7);
}

// ================= dtype detect =================
__global__ __launch_bounds__(256) void detect_kernel(const u32* __restrict__ embw,
                                                     int* __restrict__ flag) {
    int z = 0, big = 0;
    for (int i = threadIdx.x; i < 8192; i += 256) {
        u32 w = embw[i];
        u32 lo = w & 0xffffu;
        if (lo == 0u) z++;
        else if (((lo >> 7) & 0xffu) >= 0xC0u) big++;
    }
#pragma unroll
    for (int off = 32; off > 0; off >>= 1) {
        z   += __shfl_xor(z, off, 64);
        big += __shfl_xor(big, off, 64);
    }
    __shared__ int zz[4], bb[4];
    if ((threadIdx.x & 63) == 0) { zz[threadIdx.x >> 6] = z; bb[threadIdx.x >> 6] = big; }
    __syncthreads();
    if (threadIdx.x == 0) {
        int Z = zz[0] + zz[1] + zz[2] + zz[3];
        int Bc = bb[0] + bb[1] + bb[2] + bb[3];
        flag[0] = (Z > 4096 || Bc > 16) ? 1 : 0;   // 1 = fp32 storage
    }
}

// ================= convert all float inputs -> canonical bf16 =================
struct Ptrs { const void* p[17]; };

__global__ __launch_bounds__(256) void convert_kernel(Ptrs ps, u16* __restrict__ canon,
                                                      const int* __restrict__ flag) {
    const int cnt[17] = {16384,32768,256,32768,256,32768,256,131072,1024,131072,
                         256,256,256,256,256,1280,10};
    const int off[17] = {0,16384,49152,49408,82176,82432,115200,115456,246528,
                         247552,378624,378880,379136,379392,379648,379904,381184};
    const int bst[18] = {0,8,24,25,41,42,58,59,123,124,188,189,190,191,192,193,194,195};
    const int isf = *flag;
    const int blk = blockIdx.x;
    int idx = 0;
#pragma unroll
    for (int i = 0; i < 17; ++i) if (blk >= bst[i + 1]) idx = i + 1;
    const int local = blk - bst[idx];
    const int n = cnt[idx];
    const void* sp = ps.p[idx];
    u16* dp = canon + off[idx];
#pragma unroll
    for (int j = 0; j < 8; ++j) {
        int e = local * 2048 + j * 256 + threadIdx.x;
        if (e < n) {
            u16 v = isf ? f2b(((const float*)sp)[e]) : ((const u16*)sp)[e];
            dp[e] = v;
        }
    }
}

// ================= positional-encoding table (trig once, f32) =================
__global__ __launch_bounds__(256) void pe_kernel(float* __restrict__ PE) {
    int idx = blockIdx.x * 256 + threadIdx.x;   // 16384 = 256 s × 64 d2
    int s = idx >> 6, d2 = idx & 63;
    float ang = (float)s * expf((float)(d2 * 2) * -0.0719557841560639f); // -ln(10000)/128
    float2 sc; sc.x = sinf(ang); sc.y = cosf(ang);
    *(float2*)(PE + s * DM + d2 * 2) = sc;
}

// ================= embed + positional encoding → X bf16 (vectorized ×4) ========
__global__ __launch_bounds__(256) void embed_kernel(const int* __restrict__ src,
                                                    const u16* __restrict__ emb,
                                                    const float* __restrict__ PE,
                                                    u16* __restrict__ X) {
    int idx = blockIdx.x * 256 + threadIdx.x;      // one per 8 bf16 (16B)
    int dq = idx & 15;             // d-quarter: d = dq*8
    int m = idx >> 4;              // s*512 + b
    int s = m >> 9;
    int b = m & 511;
    int tok = src[b * S_LEN + s];
    int d = dq * 8;
    uint4 ev = *(const uint4*)(emb + tok * DM + d);
    const float* pe = PE + s * DM + d;
    u16 o[8];
    const u32 ew[4] = {ev.x, ev.y, ev.z, ev.w};
#pragma unroll
    for (int p = 0; p < 4; ++p) {
        float e0 = __uint_as_float((ew[p] & 0xffffu) << 16) * 11.3137084989847604f;
        float e1 = __uint_as_float(ew[p] & 0xffff0000u)     * 11.3137084989847604f;
        o[p * 2]     = f2b(e0 + pe[p * 2]);
        o[p * 2 + 1] = f2b(e1 + pe[p * 2 + 1]);
    }
    uint4 wv;
    wv.x = (u32)o[0] | ((u32)o[1] << 16);
    wv.y = (u32)o[2] | ((u32)o[3] << 16);
    wv.z = (u32)o[4] | ((u32)o[5] << 16);
    wv.w = (u32)o[6] | ((u32)o[7] << 16);
    *(uint4*)(X + (size_t)m * DM + d) = wv;
}

// ================= kvproj (MFMA): per-s K/V proj + KV^T + Ksum =================
// R9 version. block = s, 4 waves. Weights VGPR-resident as B-frags. Xs staging
// via global_load_lds w/ pre-swizzled source; next chunk's DMA flies under KV MFMAs.
__global__ __launch_bounds__(256) void kvproj_kernel(
    const u16* __restrict__ X, const u16* __restrict__ Wk, const u16* __restrict__ bk,
    const u16* __restrict__ Wv, const u16* __restrict__ bv,
    u16* __restrict__ KVt, float* __restrict__ Ksum)
{
    __shared__ __align__(16) char sm_[49152];
    u16* Xs = (u16*)sm_;             // 16KB: 64 rows x 128 k, sw16 (src-preswizzled)
    u16* Kt = (u16*)(sm_ + 16384);   // 16KB: 128 d x 64 b, 8-slot swizzle
    u16* Vt = (u16*)(sm_ + 32768);   // 16KB: 128 e x 64 b
    const int s = blockIdx.x, t = threadIdx.x;
    const int w = t >> 6, quad = (t >> 4) & 3, lr = t & 15;
    const int l = t & 63;
    const u16* Xg = X + (size_t)s * B_SZ * DM;

#define STAGE_XS(B0)                                                            \
    {                                                                           \
        _Pragma("unroll")                                                       \
        for (int i = 0; i < 4; ++i) {                                           \
            int r = w * 16 + i * 4 + (l >> 4);                                  \
            int ss = (l & 15) ^ (r & 15);                                       \
            gld_lds16(Xg + (size_t)((B0) + r) * DM + (ss << 3),                 \
                      Xs + w * 2048 + i * 512);                                 \
        }                                                                       \
    }

    // VGPR weight B-frags: e = w*32 + ct*16 + lr, k = kc*32 + quad*8
    bf16x8 wkf[2][4], wvf[2][4];
    float kb[2], vb[2];
#pragma unroll
    for (int ct = 0; ct < 2; ++ct) {
        int e = w * 32 + ct * 16 + lr;
#pragma unroll
        for (int kc = 0; kc < 4; ++kc) {
            wkf[ct][kc] = *(const bf16x8*)(Wk + e * 128 + kc * 32 + quad * 8);
            wvf[ct][kc] = *(const bf16x8*)(Wv + e * 128 + kc * 32 + quad * 8);
        }
        kb[ct] = b2f(bk[e]);
        vb[ct] = b2f(bv[e]);
    }

    const f32x4 z4 = {0.f, 0.f, 0.f, 0.f};
    f32x4 kvacc[2][8];
#pragma unroll
    for (int dt = 0; dt < 2; ++dt)
#pragma unroll
        for (int ct = 0; ct < 8; ++ct) kvacc[dt][ct] = z4;
    float ks[2] = {0.f, 0.f};

    STAGE_XS(0)
    __syncthreads();   // DMA drained

    for (int b0 = 0; b0 < B_SZ; b0 += 64) {
        // ---- K projection: rows = chunk 64, cols = wave e-slice 32 ----
        f32x4 pa[4][2];
#pragma unroll
        for (int mt = 0; mt < 4; ++mt) { pa[mt][0] = z4; pa[mt][1] = z4; }
#pragma unroll
        for (int kc = 0; kc < 4; ++kc) {
            bf16x8 a[4];
#pragma unroll
            for (int mt = 0; mt < 4; ++mt)
                a[mt] = *(const bf16x8*)(Xs + sw16(mt * 16 + lr, kc * 32 + quad * 8));
#pragma unroll
            for (int ct = 0; ct < 2; ++ct)
#pragma unroll
                for (int mt = 0; mt < 4; ++mt)
                    pa[mt][ct] = __builtin_amdgcn_mfma_f32_16x16x32_bf16(a[mt], wkf[ct][kc], pa[mt][ct], 0, 0, 0);
        }
#pragma unroll
        for (int ct = 0; ct < 2; ++ct) {
            int e = w * 32 + ct * 16 + lr, e7 = e & 7;
#pragma unroll
            for (int mt = 0; mt < 4; ++mt) {
                u16 h[4]; float ssum = 0.f;
#pragma unroll
                for (int j = 0; j < 4; ++j) {
                    float v = fmaxf(pa[mt][ct][j] + kb[ct], 0.f) + 1e-6f;
                    h[j] = f2b(v); ssum += b2f(h[j]);
                }
                ks[ct] += ssum;
                uint2 pk; pk.x = (u32)h[0] | ((u32)h[1] << 16); pk.y = (u32)h[2] | ((u32)h[3] << 16);
                int bs = mt * 2 + (quad >> 1);          // b>>3
                *(uint2*)(Kt + e * 64 + (((bs ^ e7) & 7) << 3) + (quad & 1) * 4) = pk;
            }
        }
        // ---- V projection ----
#pragma unroll
        for (int mt = 0; mt < 4; ++mt) { pa[mt][0] = z4; pa[mt][1] = z4; }
#pragma unroll
        for (int kc = 0; kc < 4; ++kc) {
            bf16x8 a[4];
#pragma unroll
            for (int mt = 0; mt < 4; ++mt)
                a[mt] = *(const bf16x8*)(Xs + sw16(mt * 16 + lr, kc * 32 + quad * 8));
#pragma unroll
            for (int ct = 0; ct < 2; ++ct)
#pragma unroll
                for (int mt = 0; mt < 4; ++mt)
                    pa[mt][ct] = __builtin_amdgcn_mfma_f32_16x16x32_bf16(a[mt], wvf[ct][kc], pa[mt][ct], 0, 0, 0);
        }
#pragma unroll
        for (int ct = 0; ct < 2; ++ct) {
            int e = w * 32 + ct * 16 + lr, e7 = e & 7;
#pragma unroll
            for (int mt = 0; mt < 4; ++mt) {
                u16 h[4];
#pragma unroll
                for (int j = 0; j < 4; ++j) h[j] = f2b(pa[mt][ct][j] + vb[ct]);
                uint2 pk; pk.x = (u32)h[0] | ((u32)h[1] << 16); pk.y = (u32)h[2] | ((u32)h[3] << 16);
                int bs = mt * 2 + (quad >> 1);
                *(uint2*)(Vt + e * 64 + (((bs ^ e7) & 7) << 3) + (quad & 1) * 4) = pk;
            }
        }
        __syncthreads();   // all Xs reads + Kt/Vt writes complete
        if (b0 < B_SZ - 64) STAGE_XS(b0 + 64)   // DMA flies under KV accum
        // ---- KV += K^T · V  (contraction over chunk b) ----
#pragma unroll
        for (int kc = 0; kc < 2; ++kc) {
            bf16x8 ka[2];
#pragma unroll
            for (int dt = 0; dt < 2; ++dt) {
                int d = (2 * w + dt) * 16 + lr;
                ka[dt] = *(const bf16x8*)(Kt + d * 64 + ((((kc * 4 + quad) ^ (d & 7)) & 7) << 3));
            }
#pragma unroll
            for (int ct = 0; ct < 8; ++ct) {
                int e = ct * 16 + lr;
                bf16x8 vf = *(const bf16x8*)(Vt + e * 64 + ((((kc * 4 + quad) ^ (e & 7)) & 7) << 3));
                kvacc[0][ct] = __builtin_amdgcn_mfma_f32_16x16x32_bf16(ka[0], vf, kvacc[0][ct], 0, 0, 0);
                kvacc[1][ct] = __builtin_amdgcn_mfma_f32_16x16x32_bf16(ka[1], vf, kvacc[1][ct], 0, 0, 0);
            }
        }
        __syncthreads();   // Kt/Vt reads done; DMA drained for next chunk
    }
#undef STAGE_XS
    // Ksum: reduce over quad (lanes xor 16, 32), quad 0 writes
#pragma unroll
    for (int ct = 0; ct < 2; ++ct) {
        float v = ks[ct];
        v += __shfl_xor(v, 16, 64);
        v += __shfl_xor(v, 32, 64);
        if (quad == 0) Ksum[s * 128 + w * 32 + ct * 16 + lr] = v;
    }
    // KVt global bf16 [e][d]: consecutive C-regs j = consecutive d → uint2 packs
    u16* KVg = KVt + (size_t)s * (DM * DM);
#pragma unroll
    for (int dt = 0; dt < 2; ++dt) {
        int d0 = (2 * w + dt) * 16 + quad * 4;
#pragma unroll
        for (int ct = 0; ct < 8; ++ct) {
            int e = ct * 16 + lr;
            u16 h[4];
#pragma unroll
            for (int j = 0; j < 4; ++j) h[j] = f2b(kvacc[dt][ct][j]);
            uint2 pk; pk.x = (u32)h[0] | ((u32)h[1] << 16); pk.y = (u32)h[2] | ((u32)h[3] << 16);
            *(uint2*)(KVg + e * 128 + d0) = pk;
        }
    }
}

// ================= attn (MFMA): Q-proj + Q·KV·Z + residual + LN =================
// block = (s, 128-row chunk). X/Xout alias (in-place, block-disjoint rows).
// R9 version (DMA-staged Wq/Xc/KVt), unchanged.
__global__ __launch_bounds__(256) void attn_ln_kernel(
    const u16* X, const u16* __restrict__ Wq, const u16* __restrict__ bq,
    const u16* __restrict__ KVt, const float* __restrict__ Ksum,
    u16* Xout, const u16* __restrict__ g, const u16* __restrict__ beta)
{
    __shared__ __align__(16) char sm_[65536];
    u16* R1 = (u16*)sm_;            // Wq staged → Qs (A-frag layout)
    u16* R2 = (u16*)(sm_ + 32768);  // Xc staged → KVt staged
    const int blk = blockIdx.x, s = blk >> 2, rc = blk & 3, t = threadIdx.x;
    const int w = t >> 6, quad = (t >> 4) & 3, lr = t & 15;
    const int l = t & 63;
    const size_t m0 = (size_t)s * B_SZ + rc * 128;

    // ---- stage Wq → R1, Xc → R2 (DMA, src-preswizzled sw16) ----
#pragma unroll
    for (int i = 0; i < 8; ++i) {
        int r = w * 32 + i * 4 + (l >> 4);
        int ss = (l & 15) ^ (r & 15);
        gld_lds16(Wq + (size_t)r * DM + (ss << 3), R1 + w * 4096 + i * 512);
        gld_lds16(X + (m0 + r) * DM + (ss << 3),   R2 + w * 4096 + i * 512);
    }
    __syncthreads();   // DMA drained
    // ---- Q projection: wave rows w*32 .. +31 ----
    const f32x4 z4 = {0.f, 0.f, 0.f, 0.f};
    f32x4 qacc[2][8];
#pragma unroll
    for (int mt = 0; mt < 2; ++mt)
#pragma unroll
        for (int ct = 0; ct < 8; ++ct) qacc[mt][ct] = z4;
#pragma unroll
    for (int kc = 0; kc < 4; ++kc) {
        bf16x8 a[2];
#pragma unroll
        for (int mt = 0; mt < 2; ++mt)
            a[mt] = *(const bf16x8*)(R2 + sw16(w * 32 + mt * 16 + lr, kc * 32 + quad * 8));
#pragma unroll
        for (int ct = 0; ct < 8; ++ct) {
            bf16x8 wf = *(const bf16x8*)(R1 + sw16(ct * 16 + lr, kc * 32 + quad * 8));
            qacc[0][ct] = __builtin_amdgcn_mfma_f32_16x16x32_bf16(a[0], wf, qacc[0][ct], 0, 0, 0);
            qacc[1][ct] = __builtin_amdgcn_mfma_f32_16x16x32_bf16(a[1], wf, qacc[1][ct], 0, 0, 0);
        }
    }
    __syncthreads();   // Wq/Xc reads complete; regions may be overwritten
    // ---- issue KVt DMA → R2 (flies under the epilogue VALU below) ----
    const u16* KVg = KVt + (size_t)s * (DM * DM);
#pragma unroll
    for (int i = 0; i < 8; ++i) {
        int e = w * 32 + i * 4 + (l >> 4);
        int ss = (l & 15) ^ (e & 15);
        gld_lds16(KVg + (size_t)e * DM + (ss << 3), R2 + w * 4096 + i * 512);
    }
    // ---- epilogue: relu+eps, Z partials (rounded Q), transpose-store Qs ----
    float ksm[8], bqv[8];
#pragma unroll
    for (int ct = 0; ct < 8; ++ct) {
        ksm[ct] = Ksum[s * 128 + ct * 16 + lr];
        bqv[ct] = b2f(bq[ct * 16 + lr]);
    }
    float zden[2][4];
#pragma unroll
    for (int mt = 0; mt < 2; ++mt)
#pragma unroll
        for (int j = 0; j < 4; ++j) zden[mt][j] = 0.f;
#pragma unroll
    for (int mt = 0; mt < 2; ++mt)
#pragma unroll
        for (int ct = 0; ct < 8; ++ct) {
            int d = ct * 16 + lr;
#pragma unroll
            for (int j = 0; j < 4; ++j) {
                float qv = fmaxf(qacc[mt][ct][j] + bqv[ct], 0.f) + 1e-6f;
                u16 qb16 = f2b(qv);
                zden[mt][j] += b2f(qb16) * ksm[ct];
                int b = w * 32 + mt * 16 + quad * 4 + j;
                R1[sw16(b, d)] = qb16;     // Qs
            }
        }
#pragma unroll
    for (int mt = 0; mt < 2; ++mt)
#pragma unroll
        for (int j = 0; j < 4; ++j) {
            float v = zden[mt][j];
            v += __shfl_xor(v, 1, 64); v += __shfl_xor(v, 2, 64);
            v += __shfl_xor(v, 4, 64); v += __shfl_xor(v, 8, 64);
            zden[mt][j] = 1.f / (v + 1e-6f);
        }
    __syncthreads();   // KVt DMA drained; Qs writes visible
    // ---- O = Q · KV ----
    f32x4 oacc[2][8];
#pragma unroll
    for (int mt = 0; mt < 2; ++mt)
#pragma unroll
        for (int ct = 0; ct < 8; ++ct) oacc[mt][ct] = z4;
#pragma unroll
    for (int kc = 0; kc < 4; ++kc) {
        bf16x8 qa[2];
#pragma unroll
        for (int mt = 0; mt < 2; ++mt)
            qa[mt] = *(const bf16x8*)(R1 + sw16(w * 32 + mt * 16 + lr, kc * 32 + quad * 8));
#pragma unroll
        for (int ct = 0; ct < 8; ++ct) {
            bf16x8 kf = *(const bf16x8*)(R2 + sw16(ct * 16 + lr, kc * 32 + quad * 8));
            oacc[0][ct] = __builtin_amdgcn_mfma_f32_16x16x32_bf16(qa[0], kf, oacc[0][ct], 0, 0, 0);
            oacc[1][ct] = __builtin_amdgcn_mfma_f32_16x16x32_bf16(qa[1], kf, oacc[1][ct], 0, 0, 0);
        }
    }
    // ---- epilogue: *Z + residual + register-only LN ----
    float gv[8], bev[8];
#pragma unroll
    for (int ct = 0; ct < 8; ++ct) {
        gv[ct]  = b2f(g[ct * 16 + lr]);
        bev[ct] = b2f(beta[ct * 16 + lr]);
    }
#pragma unroll
    for (int mt = 0; mt < 2; ++mt)
#pragma unroll
        for (int j = 0; j < 4; ++j) {
            int b = w * 32 + mt * 16 + quad * 4 + j;
            const u16* xr = X + (m0 + b) * DM;
            float vals[8], sum = 0.f, sq = 0.f;
#pragma unroll
            for (int ct = 0; ct < 8; ++ct) {
                float v = fmaf(oacc[mt][ct][j], zden[mt][j], b2f(xr[ct * 16 + lr]));
                vals[ct] = v; sum += v; sq += v * v;
            }
            sum += __shfl_xor(sum, 1, 64); sq += __shfl_xor(sq, 1, 64);
            sum += __shfl_xor(sum, 2, 64); sq += __shfl_xor(sq, 2, 64);
            sum += __shfl_xor(sum, 4, 64); sq += __shfl_xor(sq, 4, 64);
            sum += __shfl_xor(sum, 8, 64); sq += __shfl_xor(sq, 8, 64);
            float mean = sum * 0.0078125f;
            float var  = sq * 0.0078125f - mean * mean;
            float rstd = rsqrtf(fmaxf(var, 0.f) + 1e-5f);
            u16* xo = Xout + (m0 + b) * DM;
#pragma unroll
            for (int ct = 0; ct < 8; ++ct)
                xo[ct * 16 + lr] = f2b((vals[ct] - mean) * rstd * gv[ct] + bev[ct]);
        }
}

// ================= fused MLP — 32×32×16 MFMA, split-stage schedule ============
// 64 rows/block, grid 2048, 4 waves. Same 40KB LDS layouts + STAGE macros +
// split-stage barrier schedule as R13. MFMA shape 16x16x32 → 32x32x16:
// 2× FLOP per LDS frag read → per-wave b128 reads/chunk 34 → 20.
// H: wave = (mh = w>>1, fh = w&1) 32×32 tile; A = X (af[8], VGPR); B = W1c.
// Hc writes BEFORE barrier A (cross-wave visibility via A; still 2 barriers).
// Z: wave = m-tile mh... wave = (m-tile w>>1, d-pair w&1); A = Hc; B = W2c.
// Epilogue: zs f32 overlay (row-contiguous, conflict-free) + row LN.
// 32×32 C/D map (guide-verified): col = lane&31, row = (reg&3)+8*(reg>>2)+4*(lane>>5).
__global__ __launch_bounds__(256, 4) void mlp_kernel(
    const u16* X, const u16* __restrict__ W1, const u16* __restrict__ b1,
    const u16* __restrict__ W2, const u16* __restrict__ b2,
    u16* Xout, const u16* __restrict__ g, const u16* __restrict__ beta)
{
    __shared__ __align__(16) char sm_[40960];
    u16* W1c = (u16*)sm_;             // 16KB [64 f][128 k] sw16 (src-preswizzled)
    u16* W2c = (u16*)(sm_ + 16384);   // 16KB [128 d][64 f] slot8 (src-preswizzled)
    u16* Hc  = (u16*)(sm_ + 32768);   // 8KB  [64 m][64 f] slot8
    float* zs = (float*)sm_;          // 32KB epilogue overlay (W1c+W2c dead)
    const int t = threadIdx.x;
    const int m0 = blockIdx.x * 64;
    const int w  = t >> 6;
    const int l  = t & 63;
    const int l5 = l >> 5;            // k-group / row-half selector
    const int lc = l & 31;            // lane col
    const int mh = w >> 1;            // m-tile (32 rows)
    const int fh = w & 1;             // H f-tile / Z d-pair

#define STAGE_W1(FC)                                                            \
    {                                                                           \
        _Pragma("unroll")                                                       \
        for (int i = 0; i < 4; ++i) {                                           \
            int r = w * 16 + i * 4 + (l >> 4);                                  \
            int sslot = (l & 15) ^ (r & 15);                                    \
            gld_lds16(W1 + (size_t)((FC) + r) * DM + (sslot << 3),              \
                      W1c + w * 2048 + i * 512);                                \
        }                                                                       \
    }
#define STAGE_W2(FC)                                                            \
    {                                                                           \
        _Pragma("unroll")                                                       \
        for (int i = 0; i < 4; ++i) {                                           \
            int d = w * 32 + i * 8 + (l >> 3);                                  \
            int sslot = (l & 7) ^ (d & 7);                                      \
            gld_lds16(W2 + (size_t)d * DFF + (FC) + (sslot << 3),               \
                      W2c + w * 2048 + i * 512);                                \
        }                                                                       \
    }

    // A-frags (X) VGPR-resident: row = m0 + mh*32 + lc, k = ks*16 + l5*8
    bf16x8 af[8];
    {
        const u16* xr = X + (size_t)(m0 + mh * 32 + lc) * DM + l5 * 8;
#pragma unroll
        for (int ks = 0; ks < 8; ++ks)
            af[ks] = *(const bf16x8*)(xr + ks * 16);
    }

    f32x16 zero16;
#pragma unroll
    for (int i = 0; i < 16; ++i) zero16[i] = 0.f;
    f32x16 zacc0 = zero16, zacc1 = zero16;

    STAGE_W1(0)
    STAGE_W2(0)
    __syncthreads();   // DMA drained

    for (int fc = 0; fc < DFF; fc += 64) {
        // ---- H tile (32m × 32f) = X · W1^T : 8 k-steps of 16 ----
        f32x16 hacc = zero16;
#pragma unroll
        for (int ks = 0; ks < 8; ++ks) {
            bf16x8 bf_ = *(const bf16x8*)(W1c + sw16(fh * 32 + lc, ks * 16 + l5 * 8));
            hacc = __builtin_amdgcn_mfma_f32_32x32x16_bf16(af[ks], bf_, hacc, 0, 0, 0);
        }
        // bias + relu → Hc (col f = fh*32+lc fixed per lane; 16 rows via regs)
        {
            float hbv = b2f(b1[fc + fh * 32 + lc]);
            int f = fh * 32 + lc;
#pragma unroll
            for (int p = 0; p < 16; ++p) {
                int m = mh * 32 + (p & 3) + 8 * (p >> 2) + 4 * l5;
                float v = fmaxf(hacc[p] + hbv, 0.f);
                Hc[m * 64 + ((((f >> 3) ^ (m & 7)) & 7) << 3) + (f & 7)] = f2b(v);
            }
        }
        __syncthreads();   // barrier A: W1c reads done; Hc visible; prev W2 DMA drained
        if (fc < DFF - 64) STAGE_W1(fc + 64)   // W1 DMA flies under Z MFMAs
        // ---- Z (m-tile mh × d-pair fh) += H · W2^T : 4 k-steps of 16 (f) ----
#pragma unroll
        for (int ks = 0; ks < 4; ++ks) {
            int f = ks * 16 + l5 * 8;
            int m = mh * 32 + lc;
            bf16x8 ha = *(const bf16x8*)(Hc + m * 64 + ((((f >> 3) ^ (m & 7)) & 7) << 3));
            {
                int d = (fh * 2) * 32 + lc;
                bf16x8 wb = *(const bf16x8*)(W2c + d * 64 + ((((f >> 3) ^ (d & 7)) & 7) << 3));
                zacc0 = __builtin_amdgcn_mfma_f32_32x32x16_bf16(ha, wb, zacc0, 0, 0, 0);
            }
            {
                int d = (fh * 2 + 1) * 32 + lc;
                bf16x8 wb = *(const bf16x8*)(W2c + d * 64 + ((((f >> 3) ^ (d & 7)) & 7) << 3));
                zacc1 = __builtin_amdgcn_mfma_f32_32x32x16_bf16(ha, wb, zacc1, 0, 0, 0);
            }
        }
        __syncthreads();   // barrier B: Hc/W2c reads done; W1 DMA drained
        if (fc < DFF - 64) STAGE_W2(fc + 64)   // W2 DMA flies under next H
    }
#undef STAGE_W1
#undef STAGE_W2

    // ---- epilogue: zacc (+b2) → zs f32 overlay, then per-row LN ----
    {
        float b20 = b2f(b2[(fh * 2) * 32 + lc]);
        float b21 = b2f(b2[(fh * 2 + 1) * 32 + lc]);
#pragma unroll
        for (int p = 0; p < 16; ++p) {
            int mrow = mh * 32 + (p & 3) + 8 * (p >> 2) + 4 * l5;
            zs[mrow * 128 + (fh * 2) * 32 + lc]     = zacc0[p] + b20;
            zs[mrow * 128 + (fh * 2 + 1) * 32 + lc] = zacc1[p] + b21;
        }
    }
    __syncthreads();

    float g0 = b2f(g[l]), g1v = b2f(g[64 + l]);
    float be0 = b2f(beta[l]), be1 = b2f(beta[64 + l]);
    for (int q = 0; q < 16; ++q) {
        int r = w * 16 + q;
        float v0 = zs[r * 128 + l]      + b2f(X[(size_t)(m0 + r) * DM + l]);
        float v1 = zs[r * 128 + 64 + l] + b2f(X[(size_t)(m0 + r) * DM + 64 + l]);
        float sum = v0 + v1, sq = v0 * v0 + v1 * v1;
#pragma unroll
        for (int off = 32; off > 0; off >>= 1) {
            sum += __shfl_xor(sum, off, 64);
            sq  += __shfl_xor(sq,  off, 64);
        }
        float mean = sum * 0.0078125f;
        float var  = sq * 0.0078125f - mean * mean;
        float rstd = rsqrtf(fmaxf(var, 0.f) + 1e-5f);
        Xout[(size_t)(m0 + r) * DM + l]      = f2b((v0 - mean) * rstd * g0  + be0);
        Xout[(size_t)(m0 + r) * DM + 64 + l] = f2b((v1 - mean) * rstd * g1v + be1);
    }
}

// ================= mean over S + final FC =================
__global__ __launch_bounds__(128) void pool_fc_kernel(
    const u16* __restrict__ X, const u16* __restrict__ fcw,
    const u16* __restrict__ fcb, void* __restrict__ Out,
    const int* __restrict__ flag)
{
    __shared__ float pool[128];
    const int b = blockIdx.x, t = threadIdx.x;
    float acc = 0.f;
    for (int s = 0; s < S_LEN; ++s)
        acc += b2f(X[((size_t)s * B_SZ + b) * DM + t]);
    pool[t] = acc * (1.0f / 256.0f);
    __syncthreads();
    if (t < 10) {
        float o = b2f(fcb[t]);
        for (int d = 0; d < 128; ++d) o += pool[d] * b2f(fcw[t * 128 + d]);
        if (*flag) ((float*)Out)[b * 10 + t] = o;
        else       ((u16*)Out)[b * 10 + t] = f2b(o);
    }
}

// ================= launch =================
extern "C" void kernel_launch(void* const* d_in, const int* in_sizes, int n_in,
                              void* d_out, int out_size, void* d_ws, size_t ws_size,
                              hipStream_t stream)
{
    const int* src = (const int*)d_in[0];

    // ws: X bf16 33.5MB | KVt bf16 8.4MB | Ksum 128KB | flag | canon ~0.76MB
    char* ws = (char*)d_ws;
    u16*   X    = (u16*)ws;
    u16*   KVt  = (u16*)(ws + 33554432);
    float* Ksum = (float*)(ws + 41943040);
    int*   flag = (int*)(ws + 42074112);
    u16*   cn   = (u16*)(ws + 42074368);
    // PE table (f32, 128KB) lives in KVt's space — embed runs before kvproj
    float* PE   = (float*)(ws + 33554432);

    u16* emb = cn + 0;
    u16* wq  = cn + 16384;
    u16* bq  = cn + 49152;
    u16* wk  = cn + 49408;
    u16* bk  = cn + 82176;
    u16* wv  = cn + 82432;
    u16* bvp = cn + 115200;
    u16* w1  = cn + 115456;
    u16* b1  = cn + 246528;
    u16* w2  = cn + 247552;
    u16* b2  = cn + 378624;
    u16* g1  = cn + 378880;
    u16* be1 = cn + 379136;
    u16* g2  = cn + 379392;
    u16* be2 = cn + 379648;
    u16* fcw = cn + 379904;
    u16* fcb = cn + 381184;

    detect_kernel<<<1, 256, 0, stream>>>((const u32*)d_in[1], flag);

    Ptrs ps;
    for (int i = 0; i < 17; ++i) ps.p[i] = d_in[i + 1];
    convert_kernel<<<195, 256, 0, stream>>>(ps, cn, flag);

    pe_kernel<<<64, 256, 0, stream>>>(PE);
    embed_kernel<<<MROWS * 16 / 256, 256, 0, stream>>>(src, emb, PE, X);

    for (int l = 0; l < 2; ++l) {
        kvproj_kernel<<<S_LEN, 256, 0, stream>>>(
            X, wk + l * DM * DM, bk + l * DM, wv + l * DM * DM, bvp + l * DM, KVt, Ksum);
        attn_ln_kernel<<<S_LEN * 4, 256, 0, stream>>>(
            X, wq + l * DM * DM, bq + l * DM, KVt, Ksum, X, g1 + l * DM, be1 + l * DM);
        mlp_kernel<<<MROWS / 64, 256, 0, stream>>>(
            X, w1 + l * DFF * DM, b1 + l * DFF, w2 + l * DM * DFF, b2 + l * DM,
            X, g2 + l * DM, be2 + l * DM);
    }

    pool_fc_kernel<<<B_SZ, 128, 0, stream>>>(X, fcw, fcb, d_out, flag);
}

// Round 15
// 364.626 us; speedup vs baseline: 1.1356x; 1.1356x over previous
//
#include <hip/hip_runtime.h>

typedef unsigned short u16;
typedef unsigned int u32;
typedef short bf16x8 __attribute__((ext_vector_type(8)));
typedef float f32x4 __attribute__((ext_vector_type(4)));

// ---------- bf16 helpers ----------
__device__ __forceinline__ float b2f(u16 v) { return __uint_as_float(((u32)v) << 16); }
__device__ __forceinline__ u16 f2b(float f) {   // round-to-nearest-even
    u32 x = __float_as_uint(f);
    return (u16)((x + 0x7fffu + ((x >> 16) & 1u)) >> 16);
}

// async global->LDS, 16B per lane: LDS dest = uniform base + lane*16
__device__ __forceinline__ void gld_lds16(const u16* g, u16* l) {
    __builtin_amdgcn_global_load_lds(
        (const __attribute__((address_space(1))) unsigned int*)g,
        (__attribute__((address_space(3))) unsigned int*)l,
        16, 0, 0);
}

#define S_LEN 256
#define B_SZ  512
#define DM    128
#define DFF   512
#define MROWS (S_LEN * B_SZ)   // 131072

// swizzled LDS address for a [row][128] bf16 tile, 16 slots of 8
__device__ __forceinline__ int sw16(int r, int d) {
    return r * 128 + ((((d >> 3) ^ (r & 15)) & 15) << 3) + (d & 7);
}

// ================= dtype detect =================
__global__ __launch_bounds__(256) void detect_kernel(const u32* __restrict__ embw,
                                                     int* __restrict__ flag) {
    int z = 0, big = 0;
    for (int i = threadIdx.x; i < 8192; i += 256) {
        u32 w = embw[i];
        u32 lo = w & 0xffffu;
        if (lo == 0u) z++;
        else if (((lo >> 7) & 0xffu) >= 0xC0u) big++;
    }
#pragma unroll
    for (int off = 32; off > 0; off >>= 1) {
        z   += __shfl_xor(z, off, 64);
        big += __shfl_xor(big, off, 64);
    }
    __shared__ int zz[4], bb[4];
    if ((threadIdx.x & 63) == 0) { zz[threadIdx.x >> 6] = z; bb[threadIdx.x >> 6] = big; }
    __syncthreads();
    if (threadIdx.x == 0) {
        int Z = zz[0] + zz[1] + zz[2] + zz[3];
        int Bc = bb[0] + bb[1] + bb[2] + bb[3];
        flag[0] = (Z > 4096 || Bc > 16) ? 1 : 0;   // 1 = fp32 storage
    }
}

// ================= convert all float inputs -> canonical bf16 =================
struct Ptrs { const void* p[17]; };

__global__ __launch_bounds__(256) void convert_kernel(Ptrs ps, u16* __restrict__ canon,
                                                      const int* __restrict__ flag) {
    const int cnt[17] = {16384,32768,256,32768,256,32768,256,131072,1024,131072,
                         256,256,256,256,256,1280,10};
    const int off[17] = {0,16384,49152,49408,82176,82432,115200,115456,246528,
                         247552,378624,378880,379136,379392,379648,379904,381184};
    const int bst[18] = {0,8,24,25,41,42,58,59,123,124,188,189,190,191,192,193,194,195};
    const int isf = *flag;
    const int blk = blockIdx.x;
    int idx = 0;
#pragma unroll
    for (int i = 0; i < 17; ++i) if (blk >= bst[i + 1]) idx = i + 1;
    const int local = blk - bst[idx];
    const int n = cnt[idx];
    const void* sp = ps.p[idx];
    u16* dp = canon + off[idx];
#pragma unroll
    for (int j = 0; j < 8; ++j) {
        int e = local * 2048 + j * 256 + threadIdx.x;
        if (e < n) {
            u16 v = isf ? f2b(((const float*)sp)[e]) : ((const u16*)sp)[e];
            dp[e] = v;
        }
    }
}

// ================= positional-encoding table (trig once, f32) =================
__global__ __launch_bounds__(256) void pe_kernel(float* __restrict__ PE) {
    int idx = blockIdx.x * 256 + threadIdx.x;   // 16384 = 256 s × 64 d2
    int s = idx >> 6, d2 = idx & 63;
    float ang = (float)s * expf((float)(d2 * 2) * -0.0719557841560639f); // -ln(10000)/128
    float2 sc; sc.x = sinf(ang); sc.y = cosf(ang);
    *(float2*)(PE + s * DM + d2 * 2) = sc;
}

// ================= embed + positional encoding → X bf16 (vectorized ×4) ========
__global__ __launch_bounds__(256) void embed_kernel(const int* __restrict__ src,
                                                    const u16* __restrict__ emb,
                                                    const float* __restrict__ PE,
                                                    u16* __restrict__ X) {
    int idx = blockIdx.x * 256 + threadIdx.x;      // one per 8 bf16 (16B)
    int dq = idx & 15;             // d-quarter: d = dq*8
    int m = idx >> 4;              // s*512 + b
    int s = m >> 9;
    int b = m & 511;
    int tok = src[b * S_LEN + s];
    int d = dq * 8;
    uint4 ev = *(const uint4*)(emb + tok * DM + d);
    const float* pe = PE + s * DM + d;
    u16 o[8];
    const u32 ew[4] = {ev.x, ev.y, ev.z, ev.w};
#pragma unroll
    for (int p = 0; p < 4; ++p) {
        float e0 = __uint_as_float((ew[p] & 0xffffu) << 16) * 11.3137084989847604f;
        float e1 = __uint_as_float(ew[p] & 0xffff0000u)     * 11.3137084989847604f;
        o[p * 2]     = f2b(e0 + pe[p * 2]);
        o[p * 2 + 1] = f2b(e1 + pe[p * 2 + 1]);
    }
    uint4 wv;
    wv.x = (u32)o[0] | ((u32)o[1] << 16);
    wv.y = (u32)o[2] | ((u32)o[3] << 16);
    wv.z = (u32)o[4] | ((u32)o[5] << 16);
    wv.w = (u32)o[6] | ((u32)o[7] << 16);
    *(uint4*)(X + (size_t)m * DM + d) = wv;
}

// ================= kvproj (MFMA): per-s K/V proj + KV^T + Ksum =================
// block = s, 4 waves. Weights VGPR-resident as B-frags. Xs staging via
// global_load_lds w/ pre-swizzled source; next chunk's DMA flies under KV MFMAs.
__global__ __launch_bounds__(256) void kvproj_kernel(
    const u16* __restrict__ X, const u16* __restrict__ Wk, const u16* __restrict__ bk,
    const u16* __restrict__ Wv, const u16* __restrict__ bv,
    u16* __restrict__ KVt, float* __restrict__ Ksum)
{
    __shared__ __align__(16) char sm_[49152];
    u16* Xs = (u16*)sm_;             // 16KB: 64 rows x 128 k, sw16 (src-preswizzled)
    u16* Kt = (u16*)(sm_ + 16384);   // 16KB: 128 d x 64 b, 8-slot swizzle
    u16* Vt = (u16*)(sm_ + 32768);   // 16KB: 128 e x 64 b
    const int s = blockIdx.x, t = threadIdx.x;
    const int w = t >> 6, quad = (t >> 4) & 3, lr = t & 15;
    const int l = t & 63;
    const u16* Xg = X + (size_t)s * B_SZ * DM;

#define STAGE_XS(B0)                                                            \
    {                                                                           \
        _Pragma("unroll")                                                       \
        for (int i = 0; i < 4; ++i) {                                           \
            int r = w * 16 + i * 4 + (l >> 4);                                  \
            int ss = (l & 15) ^ (r & 15);                                       \
            gld_lds16(Xg + (size_t)((B0) + r) * DM + (ss << 3),                 \
                      Xs + w * 2048 + i * 512);                                 \
        }                                                                       \
    }

    // VGPR weight B-frags: e = w*32 + ct*16 + lr, k = kc*32 + quad*8
    bf16x8 wkf[2][4], wvf[2][4];
    float kb[2], vb[2];
#pragma unroll
    for (int ct = 0; ct < 2; ++ct) {
        int e = w * 32 + ct * 16 + lr;
#pragma unroll
        for (int kc = 0; kc < 4; ++kc) {
            wkf[ct][kc] = *(const bf16x8*)(Wk + e * 128 + kc * 32 + quad * 8);
            wvf[ct][kc] = *(const bf16x8*)(Wv + e * 128 + kc * 32 + quad * 8);
        }
        kb[ct] = b2f(bk[e]);
        vb[ct] = b2f(bv[e]);
    }

    const f32x4 z4 = {0.f, 0.f, 0.f, 0.f};
    f32x4 kvacc[2][8];
#pragma unroll
    for (int dt = 0; dt < 2; ++dt)
#pragma unroll
        for (int ct = 0; ct < 8; ++ct) kvacc[dt][ct] = z4;
    float ks[2] = {0.f, 0.f};

    STAGE_XS(0)
    __syncthreads();   // DMA drained

    for (int b0 = 0; b0 < B_SZ; b0 += 64) {
        // ---- K projection: rows = chunk 64, cols = wave e-slice 32 ----
        f32x4 pa[4][2];
#pragma unroll
        for (int mt = 0; mt < 4; ++mt) { pa[mt][0] = z4; pa[mt][1] = z4; }
#pragma unroll
        for (int kc = 0; kc < 4; ++kc) {
            bf16x8 a[4];
#pragma unroll
            for (int mt = 0; mt < 4; ++mt)
                a[mt] = *(const bf16x8*)(Xs + sw16(mt * 16 + lr, kc * 32 + quad * 8));
#pragma unroll
            for (int ct = 0; ct < 2; ++ct)
#pragma unroll
                for (int mt = 0; mt < 4; ++mt)
                    pa[mt][ct] = __builtin_amdgcn_mfma_f32_16x16x32_bf16(a[mt], wkf[ct][kc], pa[mt][ct], 0, 0, 0);
        }
#pragma unroll
        for (int ct = 0; ct < 2; ++ct) {
            int e = w * 32 + ct * 16 + lr, e7 = e & 7;
#pragma unroll
            for (int mt = 0; mt < 4; ++mt) {
                u16 h[4]; float ssum = 0.f;
#pragma unroll
                for (int j = 0; j < 4; ++j) {
                    float v = fmaxf(pa[mt][ct][j] + kb[ct], 0.f) + 1e-6f;
                    h[j] = f2b(v); ssum += b2f(h[j]);
                }
                ks[ct] += ssum;
                uint2 pk; pk.x = (u32)h[0] | ((u32)h[1] << 16); pk.y = (u32)h[2] | ((u32)h[3] << 16);
                int bs = mt * 2 + (quad >> 1);          // b>>3
                *(uint2*)(Kt + e * 64 + (((bs ^ e7) & 7) << 3) + (quad & 1) * 4) = pk;
            }
        }
        // ---- V projection ----
#pragma unroll
        for (int mt = 0; mt < 4; ++mt) { pa[mt][0] = z4; pa[mt][1] = z4; }
#pragma unroll
        for (int kc = 0; kc < 4; ++kc) {
            bf16x8 a[4];
#pragma unroll
            for (int mt = 0; mt < 4; ++mt)
                a[mt] = *(const bf16x8*)(Xs + sw16(mt * 16 + lr, kc * 32 + quad * 8));
#pragma unroll
            for (int ct = 0; ct < 2; ++ct)
#pragma unroll
                for (int mt = 0; mt < 4; ++mt)
                    pa[mt][ct] = __builtin_amdgcn_mfma_f32_16x16x32_bf16(a[mt], wvf[ct][kc], pa[mt][ct], 0, 0, 0);
        }
#pragma unroll
        for (int ct = 0; ct < 2; ++ct) {
            int e = w * 32 + ct * 16 + lr, e7 = e & 7;
#pragma unroll
            for (int mt = 0; mt < 4; ++mt) {
                u16 h[4];
#pragma unroll
                for (int j = 0; j < 4; ++j) h[j] = f2b(pa[mt][ct][j] + vb[ct]);
                uint2 pk; pk.x = (u32)h[0] | ((u32)h[1] << 16); pk.y = (u32)h[2] | ((u32)h[3] << 16);
                int bs = mt * 2 + (quad >> 1);
                *(uint2*)(Vt + e * 64 + (((bs ^ e7) & 7) << 3) + (quad & 1) * 4) = pk;
            }
        }
        __syncthreads();   // all Xs reads + Kt/Vt writes complete
        if (b0 < B_SZ - 64) STAGE_XS(b0 + 64)   // DMA flies under KV accum
        // ---- KV += K^T · V  (contraction over chunk b) ----
#pragma unroll
        for (int kc = 0; kc < 2; ++kc) {
            bf16x8 ka[2];
#pragma unroll
            for (int dt = 0; dt < 2; ++dt) {
                int d = (2 * w + dt) * 16 + lr;
                ka[dt] = *(const bf16x8*)(Kt + d * 64 + ((((kc * 4 + quad) ^ (d & 7)) & 7) << 3));
            }
#pragma unroll
            for (int ct = 0; ct < 8; ++ct) {
                int e = ct * 16 + lr;
                bf16x8 vf = *(const bf16x8*)(Vt + e * 64 + ((((kc * 4 + quad) ^ (e & 7)) & 7) << 3));
                kvacc[0][ct] = __builtin_amdgcn_mfma_f32_16x16x32_bf16(ka[0], vf, kvacc[0][ct], 0, 0, 0);
                kvacc[1][ct] = __builtin_amdgcn_mfma_f32_16x16x32_bf16(ka[1], vf, kvacc[1][ct], 0, 0, 0);
            }
        }
        __syncthreads();   // Kt/Vt reads done; DMA drained for next chunk
    }
#undef STAGE_XS
    // Ksum: reduce over quad (lanes xor 16, 32), quad 0 writes
#pragma unroll
    for (int ct = 0; ct < 2; ++ct) {
        float v = ks[ct];
        v += __shfl_xor(v, 16, 64);
        v += __shfl_xor(v, 32, 64);
        if (quad == 0) Ksum[s * 128 + w * 32 + ct * 16 + lr] = v;
    }
    // KVt global bf16 [e][d]: consecutive C-regs j = consecutive d → uint2 packs
    u16* KVg = KVt + (size_t)s * (DM * DM);
#pragma unroll
    for (int dt = 0; dt < 2; ++dt) {
        int d0 = (2 * w + dt) * 16 + quad * 4;
#pragma unroll
        for (int ct = 0; ct < 8; ++ct) {
            int e = ct * 16 + lr;
            u16 h[4];
#pragma unroll
            for (int j = 0; j < 4; ++j) h[j] = f2b(kvacc[dt][ct][j]);
            uint2 pk; pk.x = (u32)h[0] | ((u32)h[1] << 16); pk.y = (u32)h[2] | ((u32)h[3] << 16);
            *(uint2*)(KVg + e * 128 + d0) = pk;
        }
    }
}

// ================= attn (MFMA): Q-proj + Q·KV·Z + residual + LN =================
// block = (s, 128-row chunk). X/Xout alias (in-place, block-disjoint rows).
// DMA-staged Wq/Xc/KVt; KVt DMA flies under the zden/Qs epilogue VALU.
__global__ __launch_bounds__(256) void attn_ln_kernel(
    const u16* X, const u16* __restrict__ Wq, const u16* __restrict__ bq,
    const u16* __restrict__ KVt, const float* __restrict__ Ksum,
    u16* Xout, const u16* __restrict__ g, const u16* __restrict__ beta)
{
    __shared__ __align__(16) char sm_[65536];
    u16* R1 = (u16*)sm_;            // Wq staged → Qs (A-frag layout)
    u16* R2 = (u16*)(sm_ + 32768);  // Xc staged → KVt staged
    const int blk = blockIdx.x, s = blk >> 2, rc = blk & 3, t = threadIdx.x;
    const int w = t >> 6, quad = (t >> 4) & 3, lr = t & 15;
    const int l = t & 63;
    const size_t m0 = (size_t)s * B_SZ + rc * 128;

    // ---- stage Wq → R1, Xc → R2 (DMA, src-preswizzled sw16) ----
#pragma unroll
    for (int i = 0; i < 8; ++i) {
        int r = w * 32 + i * 4 + (l >> 4);
        int ss = (l & 15) ^ (r & 15);
        gld_lds16(Wq + (size_t)r * DM + (ss << 3), R1 + w * 4096 + i * 512);
        gld_lds16(X + (m0 + r) * DM + (ss << 3),   R2 + w * 4096 + i * 512);
    }
    __syncthreads();   // DMA drained
    // ---- Q projection: wave rows w*32 .. +31 ----
    const f32x4 z4 = {0.f, 0.f, 0.f, 0.f};
    f32x4 qacc[2][8];
#pragma unroll
    for (int mt = 0; mt < 2; ++mt)
#pragma unroll
        for (int ct = 0; ct < 8; ++ct) qacc[mt][ct] = z4;
#pragma unroll
    for (int kc = 0; kc < 4; ++kc) {
        bf16x8 a[2];
#pragma unroll
        for (int mt = 0; mt < 2; ++mt)
            a[mt] = *(const bf16x8*)(R2 + sw16(w * 32 + mt * 16 + lr, kc * 32 + quad * 8));
#pragma unroll
        for (int ct = 0; ct < 8; ++ct) {
            bf16x8 wf = *(const bf16x8*)(R1 + sw16(ct * 16 + lr, kc * 32 + quad * 8));
            qacc[0][ct] = __builtin_amdgcn_mfma_f32_16x16x32_bf16(a[0], wf, qacc[0][ct], 0, 0, 0);
            qacc[1][ct] = __builtin_amdgcn_mfma_f32_16x16x32_bf16(a[1], wf, qacc[1][ct], 0, 0, 0);
        }
    }
    __syncthreads();   // Wq/Xc reads complete; regions may be overwritten
    // ---- issue KVt DMA → R2 (flies under the epilogue VALU below) ----
    const u16* KVg = KVt + (size_t)s * (DM * DM);
#pragma unroll
    for (int i = 0; i < 8; ++i) {
        int e = w * 32 + i * 4 + (l >> 4);
        int ss = (l & 15) ^ (e & 15);
        gld_lds16(KVg + (size_t)e * DM + (ss << 3), R2 + w * 4096 + i * 512);
    }
    // ---- epilogue: relu+eps, Z partials (rounded Q), transpose-store Qs ----
    float ksm[8], bqv[8];
#pragma unroll
    for (int ct = 0; ct < 8; ++ct) {
        ksm[ct] = Ksum[s * 128 + ct * 16 + lr];
        bqv[ct] = b2f(bq[ct * 16 + lr]);
    }
    float zden[2][4];
#pragma unroll
    for (int mt = 0; mt < 2; ++mt)
#pragma unroll
        for (int j = 0; j < 4; ++j) zden[mt][j] = 0.f;
#pragma unroll
    for (int mt = 0; mt < 2; ++mt)
#pragma unroll
        for (int ct = 0; ct < 8; ++ct) {
            int d = ct * 16 + lr;
#pragma unroll
            for (int j = 0; j < 4; ++j) {
                float qv = fmaxf(qacc[mt][ct][j] + bqv[ct], 0.f) + 1e-6f;
                u16 qb16 = f2b(qv);
                zden[mt][j] += b2f(qb16) * ksm[ct];
                int b = w * 32 + mt * 16 + quad * 4 + j;
                R1[sw16(b, d)] = qb16;     // Qs
            }
        }
#pragma unroll
    for (int mt = 0; mt < 2; ++mt)
#pragma unroll
        for (int j = 0; j < 4; ++j) {
            float v = zden[mt][j];
            v += __shfl_xor(v, 1, 64); v += __shfl_xor(v, 2, 64);
            v += __shfl_xor(v, 4, 64); v += __shfl_xor(v, 8, 64);
            zden[mt][j] = 1.f / (v + 1e-6f);
        }
    __syncthreads();   // KVt DMA drained; Qs writes visible
    // ---- O = Q · KV ----
    f32x4 oacc[2][8];
#pragma unroll
    for (int mt = 0; mt < 2; ++mt)
#pragma unroll
        for (int ct = 0; ct < 8; ++ct) oacc[mt][ct] = z4;
#pragma unroll
    for (int kc = 0; kc < 4; ++kc) {
        bf16x8 qa[2];
#pragma unroll
        for (int mt = 0; mt < 2; ++mt)
            qa[mt] = *(const bf16x8*)(R1 + sw16(w * 32 + mt * 16 + lr, kc * 32 + quad * 8));
#pragma unroll
        for (int ct = 0; ct < 8; ++ct) {
            bf16x8 kf = *(const bf16x8*)(R2 + sw16(ct * 16 + lr, kc * 32 + quad * 8));
            oacc[0][ct] = __builtin_amdgcn_mfma_f32_16x16x32_bf16(qa[0], kf, oacc[0][ct], 0, 0, 0);
            oacc[1][ct] = __builtin_amdgcn_mfma_f32_16x16x32_bf16(qa[1], kf, oacc[1][ct], 0, 0, 0);
        }
    }
    // ---- epilogue: *Z + residual + register-only LN ----
    float gv[8], bev[8];
#pragma unroll
    for (int ct = 0; ct < 8; ++ct) {
        gv[ct]  = b2f(g[ct * 16 + lr]);
        bev[ct] = b2f(beta[ct * 16 + lr]);
    }
#pragma unroll
    for (int mt = 0; mt < 2; ++mt)
#pragma unroll
        for (int j = 0; j < 4; ++j) {
            int b = w * 32 + mt * 16 + quad * 4 + j;
            const u16* xr = X + (m0 + b) * DM;
            float vals[8], sum = 0.f, sq = 0.f;
#pragma unroll
            for (int ct = 0; ct < 8; ++ct) {
                float v = fmaf(oacc[mt][ct][j], zden[mt][j], b2f(xr[ct * 16 + lr]));
                vals[ct] = v; sum += v; sq += v * v;
            }
            sum += __shfl_xor(sum, 1, 64); sq += __shfl_xor(sq, 1, 64);
            sum += __shfl_xor(sum, 2, 64); sq += __shfl_xor(sq, 2, 64);
            sum += __shfl_xor(sum, 4, 64); sq += __shfl_xor(sq, 4, 64);
            sum += __shfl_xor(sum, 8, 64); sq += __shfl_xor(sq, 8, 64);
            float mean = sum * 0.0078125f;
            float var  = sq * 0.0078125f - mean * mean;
            float rstd = rsqrtf(fmaxf(var, 0.f) + 1e-5f);
            u16* xo = Xout + (m0 + b) * DM;
#pragma unroll
            for (int ct = 0; ct < 8; ++ct)
                xo[ct * 16 + lr] = f2b((vals[ct] - mean) * rstd * gv[ct] + bev[ct]);
        }
}

// ================= fused MLP via MFMA — split-stage schedule (T14) =============
// 64 rows/block, grid 2048, 4 waves, A-frags VGPR-resident, DMA-staged weights.
// 40KB LDS (W1c 16K | W2c 16K | Hc 8K). STAGE split so each DMA hides under a
// compute phase: STAGE_W1(next) after barrier A (under Z MFMAs), STAGE_W2(next)
// after barrier B (under next H). 2 barriers/chunk. Best measured: 62.7 µs.
// NOTE: (256,5) forces VGPR 48 → 51MB scratch spill (R10); keep (256,4).
__global__ __launch_bounds__(256, 4) void mlp_kernel(
    const u16* X, const u16* __restrict__ W1, const u16* __restrict__ b1,
    const u16* __restrict__ W2, const u16* __restrict__ b2,
    u16* Xout, const u16* __restrict__ g, const u16* __restrict__ beta)
{
    __shared__ __align__(16) char sm_[40960];
    u16* W1c = (u16*)sm_;             // 16KB [64 f][128 k] sw16 (src-preswizzled)
    u16* W2c = (u16*)(sm_ + 16384);   // 16KB [128 d][64 f] slot8 (src-preswizzled)
    u16* Hc  = (u16*)(sm_ + 32768);   // 8KB  [64 m][64 f] slot8
    const int t = threadIdx.x;
    const int m0 = blockIdx.x * 64;
    const int w  = t >> 6;
    const int quad = (t >> 4) & 3;
    const int lr = t & 15;
    const int l  = t & 63;

    bf16x8 af[4];
    {
        const u16* xr = X + (size_t)(m0 + w * 16 + lr) * DM + quad * 8;
#pragma unroll
        for (int kc = 0; kc < 4; ++kc)
            af[kc] = *(const bf16x8*)(xr + kc * 32);
    }

    const f32x4 zero4 = {0.f, 0.f, 0.f, 0.f};
    f32x4 zacc[8];
#pragma unroll
    for (int ct = 0; ct < 8; ++ct) zacc[ct] = zero4;

#define STAGE_W1(FC)                                                            \
    {                                                                           \
        _Pragma("unroll")                                                       \
        for (int i = 0; i < 4; ++i) {                                           \
            int r = w * 16 + i * 4 + (l >> 4);                                  \
            int sslot = (l & 15) ^ (r & 15);                                    \
            gld_lds16(W1 + (size_t)((FC) + r) * DM + (sslot << 3),              \
                      W1c + w * 2048 + i * 512);                                \
        }                                                                       \
    }
#define STAGE_W2(FC)                                                            \
    {                                                                           \
        _Pragma("unroll")                                                       \
        for (int i = 0; i < 4; ++i) {                                           \
            int d = w * 32 + i * 8 + (l >> 3);                                  \
            int sslot = (l & 7) ^ (d & 7);                                      \
            gld_lds16(W2 + (size_t)d * DFF + (FC) + (sslot << 3),               \
                      W2c + w * 2048 + i * 512);                                \
        }                                                                       \
    }

    STAGE_W1(0)
    STAGE_W2(0)
    __syncthreads();   // DMA drained

    for (int fc = 0; fc < DFF; fc += 64) {
        // ---- H = relu(X·W1^T + b1): 16 rows/wave × 64 f (reads W1c[cur]) ----
        f32x4 hacc[4];
#pragma unroll
        for (int ct = 0; ct < 4; ++ct) hacc[ct] = zero4;
#pragma unroll
        for (int kc = 0; kc < 4; ++kc)
#pragma unroll
            for (int ct = 0; ct < 4; ++ct) {
                bf16x8 bf_ = *(const bf16x8*)(W1c + sw16(ct * 16 + lr, kc * 32 + quad * 8));
                hacc[ct] = __builtin_amdgcn_mfma_f32_16x16x32_bf16(af[kc], bf_, hacc[ct], 0, 0, 0);
            }
        __syncthreads();   // barrier A: all W1c reads done; drains prev W2 DMA
        if (fc < DFF - 64) STAGE_W1(fc + 64)   // W1 DMA flies under Z MFMAs
        // H → LDS (wave-private rows; no barrier before the zacc reads)
#pragma unroll
        for (int ct = 0; ct < 4; ++ct) {
            int f = ct * 16 + lr;
            float hbv = b2f(b1[fc + f]);
#pragma unroll
            for (int j = 0; j < 4; ++j) {
                int m = w * 16 + quad * 4 + j;
                float v = fmaxf(hacc[ct][j] + hbv, 0.f);
                Hc[m * 64 + ((((f >> 3) ^ (m & 7)) & 7) << 3) + (f & 7)] = f2b(v);
            }
        }
        // ---- Z += H·W2^T over this f-chunk (reads W2c[cur] + Hc) ----
#pragma unroll
        for (int kc = 0; kc < 2; ++kc) {
            int m = w * 16 + lr;
            bf16x8 ha = *(const bf16x8*)(Hc + m * 64 + ((((kc * 4 + quad) ^ (m & 7)) & 7) << 3));
#pragma unroll
            for (int ct = 0; ct < 8; ++ct) {
                int d = ct * 16 + lr;
                bf16x8 wb = *(const bf16x8*)(W2c + d * 64 + ((((kc * 4 + quad) ^ (d & 7)) & 7) << 3));
                zacc[ct] = __builtin_amdgcn_mfma_f32_16x16x32_bf16(ha, wb, zacc[ct], 0, 0, 0);
            }
        }
        __syncthreads();   // barrier B: W2c/Hc reads done; drains W1 DMA
        if (fc < DFF - 64) STAGE_W2(fc + 64)   // W2 DMA flies under next H
    }
#undef STAGE_W1
#undef STAGE_W2

    // ---- epilogue: bias + residual + register-only LN ----
    float gv[8], bev[8], bbv[8];
#pragma unroll
    for (int ct = 0; ct < 8; ++ct) {
        gv[ct]  = b2f(g[ct * 16 + lr]);
        bev[ct] = b2f(beta[ct * 16 + lr]);
        bbv[ct] = b2f(b2[ct * 16 + lr]);
    }
#pragma unroll
    for (int j = 0; j < 4; ++j) {
        int m = w * 16 + quad * 4 + j;
        const u16* xr = X + (size_t)(m0 + m) * DM;
        float vals[8], sum = 0.f, sq = 0.f;
#pragma unroll
        for (int ct = 0; ct < 8; ++ct) {
            float v = zacc[ct][j] + bbv[ct] + b2f(xr[ct * 16 + lr]);
            vals[ct] = v; sum += v; sq += v * v;
        }
        sum += __shfl_xor(sum, 1, 64); sq += __shfl_xor(sq, 1, 64);
        sum += __shfl_xor(sum, 2, 64); sq += __shfl_xor(sq, 2, 64);
        sum += __shfl_xor(sum, 4, 64); sq += __shfl_xor(sq, 4, 64);
        sum += __shfl_xor(sum, 8, 64); sq += __shfl_xor(sq, 8, 64);
        float mean = sum * 0.0078125f;
        float var  = sq * 0.0078125f - mean * mean;
        float rstd = rsqrtf(fmaxf(var, 0.f) + 1e-5f);
        u16* xo = Xout + (size_t)(m0 + m) * DM;
#pragma unroll
        for (int ct = 0; ct < 8; ++ct)
            xo[ct * 16 + lr] = f2b((vals[ct] - mean) * rstd * gv[ct] + bev[ct]);
    }
}

// ================= mean over S + final FC =================
__global__ __launch_bounds__(128) void pool_fc_kernel(
    const u16* __restrict__ X, const u16* __restrict__ fcw,
    const u16* __restrict__ fcb, void* __restrict__ Out,
    const int* __restrict__ flag)
{
    __shared__ float pool[128];
    const int b = blockIdx.x, t = threadIdx.x;
    float acc = 0.f;
    for (int s = 0; s < S_LEN; ++s)
        acc += b2f(X[((size_t)s * B_SZ + b) * DM + t]);
    pool[t] = acc * (1.0f / 256.0f);
    __syncthreads();
    if (t < 10) {
        float o = b2f(fcb[t]);
        for (int d = 0; d < 128; ++d) o += pool[d] * b2f(fcw[t * 128 + d]);
        if (*flag) ((float*)Out)[b * 10 + t] = o;
        else       ((u16*)Out)[b * 10 + t] = f2b(o);
    }
}

// ================= launch =================
extern "C" void kernel_launch(void* const* d_in, const int* in_sizes, int n_in,
                              void* d_out, int out_size, void* d_ws, size_t ws_size,
                              hipStream_t stream)
{
    const int* src = (const int*)d_in[0];

    // ws: X bf16 33.5MB | KVt bf16 8.4MB | Ksum 128KB | flag | canon ~0.76MB
    char* ws = (char*)d_ws;
    u16*   X    = (u16*)ws;
    u16*   KVt  = (u16*)(ws + 33554432);
    float* Ksum = (float*)(ws + 41943040);
    int*   flag = (int*)(ws + 42074112);
    u16*   cn   = (u16*)(ws + 42074368);
    // PE table (f32, 128KB) lives in KVt's space — embed runs before kvproj
    float* PE   = (float*)(ws + 33554432);

    u16* emb = cn + 0;
    u16* wq  = cn + 16384;
    u16* bq  = cn + 49152;
    u16* wk  = cn + 49408;
    u16* bk  = cn + 82176;
    u16* wv  = cn + 82432;
    u16* bvp = cn + 115200;
    u16* w1  = cn + 115456;
    u16* b1  = cn + 246528;
    u16* w2  = cn + 247552;
    u16* b2  = cn + 378624;
    u16* g1  = cn + 378880;
    u16* be1 = cn + 379136;
    u16* g2  = cn + 379392;
    u16* be2 = cn + 379648;
    u16* fcw = cn + 379904;
    u16* fcb = cn + 381184;

    detect_kernel<<<1, 256, 0, stream>>>((const u32*)d_in[1], flag);

    Ptrs ps;
    for (int i = 0; i < 17; ++i) ps.p[i] = d_in[i + 1];
    convert_kernel<<<195, 256, 0, stream>>>(ps, cn, flag);

    pe_kernel<<<64, 256, 0, stream>>>(PE);
    embed_kernel<<<MROWS * 16 / 256, 256, 0, stream>>>(src, emb, PE, X);

    for (int l = 0; l < 2; ++l) {
        kvproj_kernel<<<S_LEN, 256, 0, stream>>>(
            X, wk + l * DM * DM, bk + l * DM, wv + l * DM * DM, bvp + l * DM, KVt, Ksum);
        attn_ln_kernel<<<S_LEN * 4, 256, 0, stream>>>(
            X, wq + l * DM * DM, bq + l * DM, KVt, Ksum, X, g1 + l * DM, be1 + l * DM);
        mlp_kernel<<<MROWS / 64, 256, 0, stream>>>(
            X, w1 + l * DFF * DM, b1 + l * DFF, w2 + l * DM * DFF, b2 + l * DM,
            X, g2 + l * DM, be2 + l * DM);
    }

    pool_fc_kernel<<<B_SZ, 128, 0, stream>>>(X, fcw, fcb, d_out, flag);
}